// Round 2
// baseline (311.458 us; speedup 1.0000x reference)
//
#include <hip/hip_runtime.h>
#include <hip/hip_bf16.h>
#include <stdint.h>

// Problem constants
#define S_LEN 2048
#define DM    1024
#define NH    16
#define DKH   64
#define BATCH 2
#define M_ROWS (BATCH * S_LEN)   // 4096
#define NQKV   (3 * DM)          // 3072

typedef short          bf16x8v __attribute__((ext_vector_type(8)));
typedef float          f32x4   __attribute__((ext_vector_type(4)));
typedef unsigned short u16x4   __attribute__((ext_vector_type(4)));
typedef unsigned short u16x8   __attribute__((ext_vector_type(8)));

typedef const void __attribute__((address_space(1))) gas_void;
typedef void       __attribute__((address_space(3))) las_void;

static __device__ __forceinline__ unsigned short f2bf(float f) {
    union { float f; uint32_t u; } v; v.f = f;
    uint32_t u = v.u;
    uint32_t r = (u + 0x7fffu + ((u >> 16) & 1u)) >> 16;  // RNE
    return (unsigned short)r;
}

static __device__ __forceinline__ float rmax16(float v) {
    v = fmaxf(v, __shfl_xor(v, 1, 16));
    v = fmaxf(v, __shfl_xor(v, 2, 16));
    v = fmaxf(v, __shfl_xor(v, 4, 16));
    v = fmaxf(v, __shfl_xor(v, 8, 16));
    return v;
}
static __device__ __forceinline__ float rsum16(float v) {
    v += __shfl_xor(v, 1, 16);
    v += __shfl_xor(v, 2, 16);
    v += __shfl_xor(v, 4, 16);
    v += __shfl_xor(v, 8, 16);
    return v;
}

// ---------------- fp32 -> bf16 elementwise (x) ----------------
__global__ __launch_bounds__(256) void cvt_bf16_kernel(
    const float* __restrict__ in, unsigned short* __restrict__ out, int n8)
{
    const int i = blockIdx.x * 256 + threadIdx.x;
    if (i >= n8) return;
    f32x4 a = *(const f32x4*)(in + (size_t)i * 8);
    f32x4 b = *(const f32x4*)(in + (size_t)i * 8 + 4);
    u16x8 o;
    #pragma unroll
    for (int j = 0; j < 4; ++j) { o[j] = f2bf(a[j]); o[4 + j] = f2bf(b[j]); }
    *(u16x8*)(out + (size_t)i * 8) = o;
}

// ---------------- W [K][N] fp32 -> Wt [N][K] bf16 (tiled transpose) ----------------
__global__ __launch_bounds__(256) void transpose_w_kernel(
    const float* __restrict__ W, unsigned short* __restrict__ Wt, int K, int N)
{
    __shared__ float t[32][33];
    const int tx = threadIdx.x, ty = threadIdx.y;
    const int n0 = blockIdx.x * 32, k0 = blockIdx.y * 32;
    #pragma unroll
    for (int i = 0; i < 4; ++i)
        t[ty * 4 + i][tx] = W[(size_t)(k0 + ty * 4 + i) * N + n0 + tx];
    __syncthreads();
    #pragma unroll
    for (int i = 0; i < 4; ++i)
        Wt[(size_t)(n0 + ty * 4 + i) * K + k0 + tx] = f2bf(t[tx][ty * 4 + i]);
}

// ---------------- GEMM: C[M][N] = A[M][K] * Bt[N][K]^T + bias ----------------
// 128x128 tile, BK=32, 4 waves (2x2), each wave 64x64 via 4x4 of 16x16x32 MFMA.
// EPI==0: bf16 output; EPI==1: fp32 output.
template <int EPI>
__global__ __launch_bounds__(256) void gemm_bt_kernel(
    const unsigned short* __restrict__ A, const unsigned short* __restrict__ Bt,
    const float* __restrict__ bias, void* __restrict__ Cout,
    int M, int N, int K)
{
    __shared__ __attribute__((aligned(16))) unsigned short As[128 * 32];
    __shared__ __attribute__((aligned(16))) unsigned short Bs[128 * 32];

    const int tid  = threadIdx.x;
    const int lane = tid & 63;
    const int w    = tid >> 6;
    const int wr   = w >> 1, wc = w & 1;
    const int lr   = lane & 15, lg = lane >> 4;
    const int m0   = blockIdx.y * 128, n0 = blockIdx.x * 128;

    f32x4 acc[4][4];
    #pragma unroll
    for (int i = 0; i < 4; ++i)
        #pragma unroll
        for (int j = 0; j < 4; ++j) acc[i][j] = (f32x4){0.f, 0.f, 0.f, 0.f};

    for (int kt = 0; kt < K; kt += 32) {
        if (kt) __syncthreads();
        #pragma unroll
        for (int j = 0; j < 2; ++j) {
            const int c  = j * 256 + tid;           // chunk 0..511 (16B each)
            const int r  = c >> 2;                  // tile row 0..127
            const int kc = (c & 3) * 8;             // k element offset 0/8/16/24
            const int cb = j * 256 + (tid & ~63);   // wave-uniform chunk base
            __builtin_amdgcn_global_load_lds(
                (gas_void*)(A + (size_t)(m0 + r) * K + kt + kc),
                (las_void*)((char*)As + (size_t)cb * 16), 16, 0, 0);
            __builtin_amdgcn_global_load_lds(
                (gas_void*)(Bt + (size_t)(n0 + r) * K + kt + kc),
                (las_void*)((char*)Bs + (size_t)cb * 16), 16, 0, 0);
        }
        __syncthreads();  // drains vmcnt(0) before barrier

        bf16x8v af[4], bfv[4];
        #pragma unroll
        for (int mi = 0; mi < 4; ++mi)
            af[mi] = *(const bf16x8v*)(&As[(wr * 64 + mi * 16 + lr) * 32 + lg * 8]);
        #pragma unroll
        for (int ni = 0; ni < 4; ++ni)
            bfv[ni] = *(const bf16x8v*)(&Bs[(wc * 64 + ni * 16 + lr) * 32 + lg * 8]);
        #pragma unroll
        for (int mi = 0; mi < 4; ++mi)
            #pragma unroll
            for (int ni = 0; ni < 4; ++ni)
                acc[mi][ni] = __builtin_amdgcn_mfma_f32_16x16x32_bf16(
                    af[mi], bfv[ni], acc[mi][ni], 0, 0, 0);
    }

    // Epilogue. C/D layout: col = lane&15, row = (lane>>4)*4 + reg.
    const int grow0 = m0 + wr * 64 + lg * 4;
    const int gcol0 = n0 + wc * 64 + lr;
    #pragma unroll
    for (int mi = 0; mi < 4; ++mi)
        #pragma unroll
        for (int ni = 0; ni < 4; ++ni) {
            const int gcol = gcol0 + ni * 16;
            const float bv = bias[gcol];
            #pragma unroll
            for (int r = 0; r < 4; ++r) {
                const size_t idx = (size_t)(grow0 + mi * 16 + r) * N + gcol;
                const float v = acc[mi][ni][r] + bv;
                if (EPI == 0) ((unsigned short*)Cout)[idx] = f2bf(v);
                else          ((float*)Cout)[idx] = v;
            }
        }
}

// ---------------- split QKV -> Q,K [bh][s][64], Vt [bh][64][s] ----------------
__global__ __launch_bounds__(256) void split_qkv_kernel(
    const unsigned short* __restrict__ qkv,
    unsigned short* __restrict__ q, unsigned short* __restrict__ k,
    unsigned short* __restrict__ vt)
{
    const int tid = threadIdx.x;
    const int bh  = blockIdx.y;
    const int h   = bh & 15;
    const int b   = bh >> 4;
    const int s0  = blockIdx.x * 64;
    __shared__ __attribute__((aligned(16))) unsigned short tile[64][68];

    #pragma unroll
    for (int j = 0; j < 4; ++j) {
        const int c  = tid + j * 256;      // 0..1023 (chunks of 4 ushorts)
        const int r  = c >> 4;             // 0..63 (s row)
        const int c4 = (c & 15) * 4;       // 0..60 (dk col)
        // NOTE: qkv rows are b*S_LEN + s  (batch offset was missing in R1 — the bug)
        const size_t srow = ((size_t)b * S_LEN + s0 + r) * NQKV + h * 64 + c4;
        u16x4 vq = *(const u16x4*)(qkv + srow);
        u16x4 vk = *(const u16x4*)(qkv + srow + DM);
        u16x4 vv = *(const u16x4*)(qkv + srow + 2 * DM);
        const size_t drow = ((size_t)bh * S_LEN + s0 + r) * DKH + c4;
        *(u16x4*)(q + drow) = vq;
        *(u16x4*)(k + drow) = vk;
        *(u16x4*)&tile[r][c4] = vv;
    }
    __syncthreads();
    #pragma unroll
    for (int j = 0; j < 4; ++j) {
        const int c   = tid + j * 256;
        const int dkr = c >> 4;            // 0..63 (dk row of Vt)
        const int s4  = (c & 15) * 4;      // 0..60 (s col)
        u16x4 o;
        #pragma unroll
        for (int i = 0; i < 4; ++i) o[i] = tile[s4 + i][dkr];
        *(u16x4*)(vt + ((size_t)bh * DKH + dkr) * S_LEN + s0 + s4) = o;
    }
}

// ---------------- flash attention ----------------
// grid (S/64, B*H), 256 threads = 4 waves; wave w owns q rows [bx*64+w*16, +16).
__global__ __launch_bounds__(256) void attn_kernel(
    const unsigned short* __restrict__ Q, const unsigned short* __restrict__ K,
    const unsigned short* __restrict__ Vt, unsigned short* __restrict__ O)
{
    const int tid  = threadIdx.x;
    const int w    = tid >> 6;
    const int lane = tid & 63;
    const int lr   = lane & 15, lg = lane >> 4;
    const int bh   = blockIdx.y;
    const int b    = bh >> 4, h = bh & 15;
    const int q0   = blockIdx.x * 64 + w * 16;

    __shared__ __attribute__((aligned(16))) unsigned short Pl[4][16 * 72];
    unsigned short* Pw = &Pl[w][0];

    const unsigned short* Qb = Q + ((size_t)bh * S_LEN + q0 + lr) * DKH + lg * 8;
    const bf16x8v qf0 = *(const bf16x8v*)(Qb);
    const bf16x8v qf1 = *(const bf16x8v*)(Qb + 32);

    const unsigned short* Kb = K  + (size_t)bh * S_LEN * DKH;
    const unsigned short* Vb = Vt + (size_t)bh * DKH * S_LEN;

    float m_r[4], l_r[4];
    f32x4 oa[4];
    #pragma unroll
    for (int r = 0; r < 4; ++r) { m_r[r] = -__builtin_inff(); l_r[r] = 0.f; }
    #pragma unroll
    for (int nf = 0; nf < 4; ++nf) oa[nf] = (f32x4){0.f, 0.f, 0.f, 0.f};

    for (int kv0 = 0; kv0 < S_LEN; kv0 += 64) {
        // scores: S[16q x 64kv] = Q(16x64) . K^T
        f32x4 sc[4];
        #pragma unroll
        for (int nf = 0; nf < 4; ++nf) {
            const unsigned short* kp = Kb + (size_t)(kv0 + nf * 16 + lr) * DKH + lg * 8;
            const bf16x8v k0 = *(const bf16x8v*)(kp);
            const bf16x8v k1 = *(const bf16x8v*)(kp + 32);
            f32x4 z = (f32x4){0.f, 0.f, 0.f, 0.f};
            z = __builtin_amdgcn_mfma_f32_16x16x32_bf16(qf0, k0, z, 0, 0, 0);
            sc[nf] = __builtin_amdgcn_mfma_f32_16x16x32_bf16(qf1, k1, z, 0, 0, 0);
        }
        #pragma unroll
        for (int nf = 0; nf < 4; ++nf)
            #pragma unroll
            for (int r = 0; r < 4; ++r) sc[nf][r] *= 0.125f;  // 1/sqrt(64)

        float tm[4];
        #pragma unroll
        for (int r = 0; r < 4; ++r)
            tm[r] = rmax16(fmaxf(fmaxf(sc[0][r], sc[1][r]), fmaxf(sc[2][r], sc[3][r])));

        float corr[4], rs[4];
        #pragma unroll
        for (int r = 0; r < 4; ++r) {
            const float mn = fmaxf(m_r[r], tm[r]);
            corr[r] = __expf(m_r[r] - mn);
            m_r[r] = mn;
            rs[r] = 0.f;
        }
        #pragma unroll
        for (int nf = 0; nf < 4; ++nf)
            #pragma unroll
            for (int r = 0; r < 4; ++r) {
                const float p = __expf(sc[nf][r] - m_r[r]);
                sc[nf][r] = p;
                rs[r] += p;
            }
        #pragma unroll
        for (int r = 0; r < 4; ++r) {
            rs[r] = rsum16(rs[r]);
            l_r[r] = l_r[r] * corr[r] + rs[r];
        }
        #pragma unroll
        for (int nf = 0; nf < 4; ++nf)
            #pragma unroll
            for (int r = 0; r < 4; ++r) oa[nf][r] *= corr[r];

        // P tile to LDS (C/D layout -> A-operand layout round trip), stride 72 (pad)
        #pragma unroll
        for (int nf = 0; nf < 4; ++nf)
            #pragma unroll
            for (int r = 0; r < 4; ++r)
                Pw[(lg * 4 + r) * 72 + nf * 16 + lr] = f2bf(sc[nf][r]);

        const bf16x8v pa0 = *(const bf16x8v*)(&Pw[lr * 72 + lg * 8]);
        const bf16x8v pa1 = *(const bf16x8v*)(&Pw[lr * 72 + 32 + lg * 8]);

        #pragma unroll
        for (int nf = 0; nf < 4; ++nf) {
            const unsigned short* vp = Vb + (size_t)(nf * 16 + lr) * S_LEN + kv0 + lg * 8;
            const bf16x8v v0 = *(const bf16x8v*)(vp);
            const bf16x8v v1 = *(const bf16x8v*)(vp + 32);
            oa[nf] = __builtin_amdgcn_mfma_f32_16x16x32_bf16(pa0, v0, oa[nf], 0, 0, 0);
            oa[nf] = __builtin_amdgcn_mfma_f32_16x16x32_bf16(pa1, v1, oa[nf], 0, 0, 0);
        }
    }

    #pragma unroll
    for (int r = 0; r < 4; ++r) l_r[r] = 1.0f / l_r[r];
    #pragma unroll
    for (int nf = 0; nf < 4; ++nf)
        #pragma unroll
        for (int r = 0; r < 4; ++r) {
            const size_t row = (size_t)b * S_LEN + q0 + lg * 4 + r;
            O[row * DM + h * 64 + nf * 16 + lr] = f2bf(oa[nf][r] * l_r[r]);
        }
}

// ---------------- host launcher ----------------
extern "C" void kernel_launch(void* const* d_in, const int* in_sizes, int n_in,
                              void* d_out, int out_size, void* d_ws, size_t ws_size,
                              hipStream_t stream)
{
    const float* x    = (const float*)d_in[0];
    const float* Wqkv = (const float*)d_in[1];
    const float* bqkv = (const float*)d_in[2];
    const float* Wout = (const float*)d_in[3];
    const float* bout = (const float*)d_in[4];
    float* out = (float*)d_out;

    char* ws = (char*)d_ws;
    // layout (bytes):
    //  [0,            8388608)  xb   (x bf16)          -- later reused as Q
    //  [8388608,     14680064)  wqkv_t bf16 [3072][1024]
    //  [14680064,    16777216)  wout_t bf16 [1024][1024]
    //  [16777216,    41943040)  qkvb bf16 [4096][3072]  -- later reused as attn_out
    //  [41943040,    50331648)  kb bf16 [32][2048][64]
    //  [50331648,    58720256)  vtb bf16 [32][64][2048]
    unsigned short* xb     = (unsigned short*)(ws);
    unsigned short* wqkv_t = (unsigned short*)(ws + 8388608);
    unsigned short* wout_t = (unsigned short*)(ws + 14680064);
    unsigned short* qkvb   = (unsigned short*)(ws + 16777216);
    unsigned short* kb     = (unsigned short*)(ws + 41943040);
    unsigned short* vtb    = (unsigned short*)(ws + 50331648);
    unsigned short* qb     = xb;    // alias: x bf16 dead after QKV GEMM
    unsigned short* attn_o = qkvb;  // alias: qkv dead after split

    cvt_bf16_kernel<<<2048, 256, 0, stream>>>(x, xb, (M_ROWS * DM) / 8);
    transpose_w_kernel<<<dim3(NQKV / 32, DM / 32), dim3(32, 8), 0, stream>>>(Wqkv, wqkv_t, DM, NQKV);
    transpose_w_kernel<<<dim3(DM / 32, DM / 32), dim3(32, 8), 0, stream>>>(Wout, wout_t, DM, DM);
    gemm_bt_kernel<0><<<dim3(NQKV / 128, M_ROWS / 128), 256, 0, stream>>>(
        xb, wqkv_t, bqkv, (void*)qkvb, M_ROWS, NQKV, DM);
    split_qkv_kernel<<<dim3(S_LEN / 64, BATCH * NH), 256, 0, stream>>>(qkvb, qb, kb, vtb);
    attn_kernel<<<dim3(S_LEN / 64, BATCH * NH), 256, 0, stream>>>(qb, kb, vtb, attn_o);
    gemm_bt_kernel<1><<<dim3(DM / 128, M_ROWS / 128), 256, 0, stream>>>(
        attn_o, wout_t, bout, (void*)out, M_ROWS, DM, DM);
}

// Round 3
// 310.770 us; speedup vs baseline: 1.0022x; 1.0022x over previous
//
#include <hip/hip_runtime.h>
#include <hip/hip_bf16.h>
#include <stdint.h>

// Problem constants
#define S_LEN 2048
#define DM    1024
#define NH    16
#define DKH   64
#define BATCH 2
#define M_ROWS (BATCH * S_LEN)   // 4096
#define NQKV   (3 * DM)          // 3072

typedef short          bf16x8v __attribute__((ext_vector_type(8)));
typedef float          f32x4   __attribute__((ext_vector_type(4)));
typedef unsigned short u16x4   __attribute__((ext_vector_type(4)));
typedef unsigned short u16x8   __attribute__((ext_vector_type(8)));

typedef const void __attribute__((address_space(1))) gas_void;
typedef void       __attribute__((address_space(3))) las_void;

static __device__ __forceinline__ unsigned short f2bf(float f) {
    union { float f; uint32_t u; } v; v.f = f;
    uint32_t u = v.u;
    uint32_t r = (u + 0x7fffu + ((u >> 16) & 1u)) >> 16;  // RNE
    return (unsigned short)r;
}

static __device__ __forceinline__ float rmax16(float v) {
    v = fmaxf(v, __shfl_xor(v, 1, 16));
    v = fmaxf(v, __shfl_xor(v, 2, 16));
    v = fmaxf(v, __shfl_xor(v, 4, 16));
    v = fmaxf(v, __shfl_xor(v, 8, 16));
    return v;
}
static __device__ __forceinline__ float rsum16(float v) {
    v += __shfl_xor(v, 1, 16);
    v += __shfl_xor(v, 2, 16);
    v += __shfl_xor(v, 4, 16);
    v += __shfl_xor(v, 8, 16);
    return v;
}

// ---------------- fp32 -> bf16 elementwise (x) ----------------
__global__ __launch_bounds__(256) void cvt_bf16_kernel(
    const float* __restrict__ in, unsigned short* __restrict__ out, int n8)
{
    const int i = blockIdx.x * 256 + threadIdx.x;
    if (i >= n8) return;
    f32x4 a = *(const f32x4*)(in + (size_t)i * 8);
    f32x4 b = *(const f32x4*)(in + (size_t)i * 8 + 4);
    u16x8 o;
    #pragma unroll
    for (int j = 0; j < 4; ++j) { o[j] = f2bf(a[j]); o[4 + j] = f2bf(b[j]); }
    *(u16x8*)(out + (size_t)i * 8) = o;
}

// ---------------- W [K][N] fp32 -> Wt [N][K] bf16 (tiled transpose) ----------------
__global__ __launch_bounds__(256) void transpose_w_kernel(
    const float* __restrict__ W, unsigned short* __restrict__ Wt, int K, int N)
{
    __shared__ float t[32][33];
    const int tx = threadIdx.x, ty = threadIdx.y;
    const int n0 = blockIdx.x * 32, k0 = blockIdx.y * 32;
    #pragma unroll
    for (int i = 0; i < 4; ++i)
        t[ty * 4 + i][tx] = W[(size_t)(k0 + ty * 4 + i) * N + n0 + tx];
    __syncthreads();
    #pragma unroll
    for (int i = 0; i < 4; ++i)
        Wt[(size_t)(n0 + ty * 4 + i) * K + k0 + tx] = f2bf(t[tx][ty * 4 + i]);
}

// ---------------- GEMM: C[M][N] = A[M][K] * Bt[N][K]^T + bias ----------------
// 128x128 tile, BK=32, 4 waves (2x2), each wave 64x64 via 4x4 of 16x16x32 MFMA.
// EPI==0: bf16 output; EPI==1: fp32 output.
template <int EPI>
__global__ __launch_bounds__(256) void gemm_bt_kernel(
    const unsigned short* __restrict__ A, const unsigned short* __restrict__ Bt,
    const float* __restrict__ bias, void* __restrict__ Cout,
    int M, int N, int K)
{
    __shared__ __attribute__((aligned(16))) unsigned short As[128 * 32];
    __shared__ __attribute__((aligned(16))) unsigned short Bs[128 * 32];

    const int tid  = threadIdx.x;
    const int lane = tid & 63;
    const int w    = tid >> 6;
    const int wr   = w >> 1, wc = w & 1;
    const int lr   = lane & 15, lg = lane >> 4;
    const int m0   = blockIdx.y * 128, n0 = blockIdx.x * 128;

    f32x4 acc[4][4];
    #pragma unroll
    for (int i = 0; i < 4; ++i)
        #pragma unroll
        for (int j = 0; j < 4; ++j) acc[i][j] = (f32x4){0.f, 0.f, 0.f, 0.f};

    for (int kt = 0; kt < K; kt += 32) {
        if (kt) __syncthreads();
        #pragma unroll
        for (int j = 0; j < 2; ++j) {
            const int c  = j * 256 + tid;           // chunk 0..511 (16B each)
            const int r  = c >> 2;                  // tile row 0..127
            const int kc = (c & 3) * 8;             // k element offset 0/8/16/24
            const int cb = j * 256 + (tid & ~63);   // wave-uniform chunk base
            __builtin_amdgcn_global_load_lds(
                (gas_void*)(A + (size_t)(m0 + r) * K + kt + kc),
                (las_void*)((char*)As + (size_t)cb * 16), 16, 0, 0);
            __builtin_amdgcn_global_load_lds(
                (gas_void*)(Bt + (size_t)(n0 + r) * K + kt + kc),
                (las_void*)((char*)Bs + (size_t)cb * 16), 16, 0, 0);
        }
        __syncthreads();  // drains vmcnt(0) before barrier

        bf16x8v af[4], bfv[4];
        #pragma unroll
        for (int mi = 0; mi < 4; ++mi)
            af[mi] = *(const bf16x8v*)(&As[(wr * 64 + mi * 16 + lr) * 32 + lg * 8]);
        #pragma unroll
        for (int ni = 0; ni < 4; ++ni)
            bfv[ni] = *(const bf16x8v*)(&Bs[(wc * 64 + ni * 16 + lr) * 32 + lg * 8]);
        #pragma unroll
        for (int mi = 0; mi < 4; ++mi)
            #pragma unroll
            for (int ni = 0; ni < 4; ++ni)
                acc[mi][ni] = __builtin_amdgcn_mfma_f32_16x16x32_bf16(
                    af[mi], bfv[ni], acc[mi][ni], 0, 0, 0);
    }

    // Epilogue. C/D layout: col = lane&15, row = (lane>>4)*4 + reg.
    const int grow0 = m0 + wr * 64 + lg * 4;
    const int gcol0 = n0 + wc * 64 + lr;
    #pragma unroll
    for (int mi = 0; mi < 4; ++mi)
        #pragma unroll
        for (int ni = 0; ni < 4; ++ni) {
            const int gcol = gcol0 + ni * 16;
            const float bv = bias[gcol];
            #pragma unroll
            for (int r = 0; r < 4; ++r) {
                const size_t idx = (size_t)(grow0 + mi * 16 + r) * N + gcol;
                const float v = acc[mi][ni][r] + bv;
                if (EPI == 0) ((unsigned short*)Cout)[idx] = f2bf(v);
                else          ((float*)Cout)[idx] = v;
            }
        }
}

// ---------------- split QKV -> Q,K [bh][s][64], Vt [bh][64][s] ----------------
__global__ __launch_bounds__(256) void split_qkv_kernel(
    const unsigned short* __restrict__ qkv,
    unsigned short* __restrict__ q, unsigned short* __restrict__ k,
    unsigned short* __restrict__ vt)
{
    const int tid = threadIdx.x;
    const int bh  = blockIdx.y;
    const int h   = bh & 15;
    const int b   = bh >> 4;
    const int s0  = blockIdx.x * 64;
    __shared__ __attribute__((aligned(16))) unsigned short tile[64][68];

    #pragma unroll
    for (int j = 0; j < 4; ++j) {
        const int c  = tid + j * 256;      // 0..1023 (chunks of 4 ushorts)
        const int r  = c >> 4;             // 0..63 (s row)
        const int c4 = (c & 15) * 4;       // 0..60 (dk col)
        const size_t srow = ((size_t)b * S_LEN + s0 + r) * NQKV + h * 64 + c4;
        u16x4 vq = *(const u16x4*)(qkv + srow);
        u16x4 vk = *(const u16x4*)(qkv + srow + DM);
        u16x4 vv = *(const u16x4*)(qkv + srow + 2 * DM);
        const size_t drow = ((size_t)bh * S_LEN + s0 + r) * DKH + c4;
        *(u16x4*)(q + drow) = vq;
        *(u16x4*)(k + drow) = vk;
        *(u16x4*)&tile[r][c4] = vv;
    }
    __syncthreads();
    #pragma unroll
    for (int j = 0; j < 4; ++j) {
        const int c   = tid + j * 256;
        const int dkr = c >> 4;            // 0..63 (dk row of Vt)
        const int s4  = (c & 15) * 4;      // 0..60 (s col)
        u16x4 o;
        #pragma unroll
        for (int i = 0; i < 4; ++i) o[i] = tile[s4 + i][dkr];
        *(u16x4*)(vt + ((size_t)bh * DKH + dkr) * S_LEN + s0 + s4) = o;
    }
}

// ---------------- flash attention ----------------
// grid (S/64, B*H) flattened+swizzled; 256 threads = 4 independent waves,
// wave w owns q rows [bx*64+w*16, +16). Register-double-buffered K, early V.
__global__ __launch_bounds__(256) void attn_kernel(
    const unsigned short* __restrict__ Q, const unsigned short* __restrict__ K,
    const unsigned short* __restrict__ Vt, unsigned short* __restrict__ O)
{
    const int tid  = threadIdx.x;
    const int w    = tid >> 6;
    const int lane = tid & 63;
    const int lr   = lane & 15, lg = lane >> 4;

    // T1: XCD-chunked swizzle. 1024 blocks = 8 XCDs x 128. Consecutive HW
    // dispatch IDs round-robin XCDs, so (flat&7) selects the XCD and each
    // XCD sees a contiguous 128-block run = 4 heads -> 2MB KV fits its L2.
    const int flat = blockIdx.y * 32 + blockIdx.x;
    const int virt = (flat & 7) * 128 + (flat >> 3);
    const int bx   = virt & 31;
    const int bh   = virt >> 5;

    const int b    = bh >> 4, h = bh & 15;
    const int q0   = bx * 64 + w * 16;

    __shared__ __attribute__((aligned(16))) unsigned short Pl[4][16 * 72];
    unsigned short* Pw = &Pl[w][0];

    const unsigned short* Qb = Q + ((size_t)bh * S_LEN + q0 + lr) * DKH + lg * 8;
    const bf16x8v qf0 = *(const bf16x8v*)(Qb);
    const bf16x8v qf1 = *(const bf16x8v*)(Qb + 32);

    const unsigned short* Kb = K  + (size_t)bh * S_LEN * DKH;
    const unsigned short* Vb = Vt + (size_t)bh * DKH * S_LEN;

    float m_r[4], l_r[4];
    f32x4 oa[4];
    #pragma unroll
    for (int r = 0; r < 4; ++r) { m_r[r] = -__builtin_inff(); l_r[r] = 0.f; }
    #pragma unroll
    for (int nf = 0; nf < 4; ++nf) oa[nf] = (f32x4){0.f, 0.f, 0.f, 0.f};

    // Prologue: K fragments for tile 0.
    bf16x8v kc0[4], kc1[4];
    #pragma unroll
    for (int nf = 0; nf < 4; ++nf) {
        const unsigned short* kp = Kb + (size_t)(nf * 16 + lr) * DKH + lg * 8;
        kc0[nf] = *(const bf16x8v*)(kp);
        kc1[nf] = *(const bf16x8v*)(kp + 32);
    }

    for (int kv0 = 0; kv0 < S_LEN; kv0 += 64) {
        // Early-issue V loads for THIS tile (consumed after softmax, ~400cy cover).
        bf16x8v vc0[4], vc1[4];
        #pragma unroll
        for (int nf = 0; nf < 4; ++nf) {
            const unsigned short* vp = Vb + (size_t)(nf * 16 + lr) * S_LEN + kv0 + lg * 8;
            vc0[nf] = *(const bf16x8v*)(vp);
            vc1[nf] = *(const bf16x8v*)(vp + 32);
        }

        // scores: S[16q x 64kv] = Q(16x64) . K^T   (raw, scale folded into exp)
        f32x4 sc[4];
        __builtin_amdgcn_s_setprio(1);
        #pragma unroll
        for (int nf = 0; nf < 4; ++nf) {
            f32x4 z = (f32x4){0.f, 0.f, 0.f, 0.f};
            z = __builtin_amdgcn_mfma_f32_16x16x32_bf16(qf0, kc0[nf], z, 0, 0, 0);
            sc[nf] = __builtin_amdgcn_mfma_f32_16x16x32_bf16(qf1, kc1[nf], z, 0, 0, 0);
        }
        __builtin_amdgcn_s_setprio(0);

        // Prefetch NEXT tile's K fragments (old kc dead after the MFMAs above).
        if (kv0 + 64 < S_LEN) {
            #pragma unroll
            for (int nf = 0; nf < 4; ++nf) {
                const unsigned short* kp =
                    Kb + (size_t)(kv0 + 64 + nf * 16 + lr) * DKH + lg * 8;
                kc0[nf] = *(const bf16x8v*)(kp);
                kc1[nf] = *(const bf16x8v*)(kp + 32);
            }
        }

        // Online softmax in RAW score domain: softmax(s/8) = exp((s-m)/8)/sum.
        float tm[4];
        #pragma unroll
        for (int r = 0; r < 4; ++r)
            tm[r] = rmax16(fmaxf(fmaxf(sc[0][r], sc[1][r]), fmaxf(sc[2][r], sc[3][r])));

        float corr[4], rs[4];
        #pragma unroll
        for (int r = 0; r < 4; ++r) {
            const float mn = fmaxf(m_r[r], tm[r]);
            corr[r] = __expf((m_r[r] - mn) * 0.125f);
            m_r[r] = mn;
            rs[r] = 0.f;
        }
        #pragma unroll
        for (int nf = 0; nf < 4; ++nf)
            #pragma unroll
            for (int r = 0; r < 4; ++r) {
                const float p = __expf((sc[nf][r] - m_r[r]) * 0.125f);
                sc[nf][r] = p;
                rs[r] += p;
            }
        #pragma unroll
        for (int r = 0; r < 4; ++r) {
            rs[r] = rsum16(rs[r]);
            l_r[r] = l_r[r] * corr[r] + rs[r];
        }
        #pragma unroll
        for (int nf = 0; nf < 4; ++nf)
            #pragma unroll
            for (int r = 0; r < 4; ++r) oa[nf][r] *= corr[r];

        // P tile to LDS (C/D layout -> A-operand layout round trip), stride 72 (pad)
        #pragma unroll
        for (int nf = 0; nf < 4; ++nf)
            #pragma unroll
            for (int r = 0; r < 4; ++r)
                Pw[(lg * 4 + r) * 72 + nf * 16 + lr] = f2bf(sc[nf][r]);

        const bf16x8v pa0 = *(const bf16x8v*)(&Pw[lr * 72 + lg * 8]);
        const bf16x8v pa1 = *(const bf16x8v*)(&Pw[lr * 72 + 32 + lg * 8]);

        __builtin_amdgcn_s_setprio(1);
        #pragma unroll
        for (int nf = 0; nf < 4; ++nf) {
            oa[nf] = __builtin_amdgcn_mfma_f32_16x16x32_bf16(pa0, vc0[nf], oa[nf], 0, 0, 0);
            oa[nf] = __builtin_amdgcn_mfma_f32_16x16x32_bf16(pa1, vc1[nf], oa[nf], 0, 0, 0);
        }
        __builtin_amdgcn_s_setprio(0);
    }

    #pragma unroll
    for (int r = 0; r < 4; ++r) l_r[r] = 1.0f / l_r[r];
    #pragma unroll
    for (int nf = 0; nf < 4; ++nf)
        #pragma unroll
        for (int r = 0; r < 4; ++r) {
            const size_t row = (size_t)b * S_LEN + q0 + lg * 4 + r;
            O[row * DM + h * 64 + nf * 16 + lr] = f2bf(oa[nf][r] * l_r[r]);
        }
}

// ---------------- host launcher ----------------
extern "C" void kernel_launch(void* const* d_in, const int* in_sizes, int n_in,
                              void* d_out, int out_size, void* d_ws, size_t ws_size,
                              hipStream_t stream)
{
    const float* x    = (const float*)d_in[0];
    const float* Wqkv = (const float*)d_in[1];
    const float* bqkv = (const float*)d_in[2];
    const float* Wout = (const float*)d_in[3];
    const float* bout = (const float*)d_in[4];
    float* out = (float*)d_out;

    char* ws = (char*)d_ws;
    // layout (bytes):
    //  [0,            8388608)  xb   (x bf16)          -- later reused as Q
    //  [8388608,     14680064)  wqkv_t bf16 [3072][1024]
    //  [14680064,    16777216)  wout_t bf16 [1024][1024]
    //  [16777216,    41943040)  qkvb bf16 [4096][3072]  -- later reused as attn_out
    //  [41943040,    50331648)  kb bf16 [32][2048][64]
    //  [50331648,    58720256)  vtb bf16 [32][64][2048]
    unsigned short* xb     = (unsigned short*)(ws);
    unsigned short* wqkv_t = (unsigned short*)(ws + 8388608);
    unsigned short* wout_t = (unsigned short*)(ws + 14680064);
    unsigned short* qkvb   = (unsigned short*)(ws + 16777216);
    unsigned short* kb     = (unsigned short*)(ws + 41943040);
    unsigned short* vtb    = (unsigned short*)(ws + 50331648);
    unsigned short* qb     = xb;    // alias: x bf16 dead after QKV GEMM
    unsigned short* attn_o = qkvb;  // alias: qkv dead after split

    cvt_bf16_kernel<<<2048, 256, 0, stream>>>(x, xb, (M_ROWS * DM) / 8);
    transpose_w_kernel<<<dim3(NQKV / 32, DM / 32), dim3(32, 8), 0, stream>>>(Wqkv, wqkv_t, DM, NQKV);
    transpose_w_kernel<<<dim3(DM / 32, DM / 32), dim3(32, 8), 0, stream>>>(Wout, wout_t, DM, DM);
    gemm_bt_kernel<0><<<dim3(NQKV / 128, M_ROWS / 128), 256, 0, stream>>>(
        xb, wqkv_t, bqkv, (void*)qkvb, M_ROWS, NQKV, DM);
    split_qkv_kernel<<<dim3(S_LEN / 64, BATCH * NH), 256, 0, stream>>>(qkvb, qb, kb, vtb);
    attn_kernel<<<dim3(S_LEN / 64, BATCH * NH), 256, 0, stream>>>(qb, kb, vtb, attn_o);
    gemm_bt_kernel<1><<<dim3(DM / 128, M_ROWS / 128), 256, 0, stream>>>(
        attn_o, wout_t, bout, (void*)out, M_ROWS, DM, DM);
}

// Round 4
// 202.743 us; speedup vs baseline: 1.5362x; 1.5328x over previous
//
#include <hip/hip_runtime.h>
#include <hip/hip_bf16.h>
#include <stdint.h>

// Problem constants
#define S_LEN 2048
#define DM    1024
#define NH    16
#define DKH   64
#define BATCH 2
#define M_ROWS (BATCH * S_LEN)   // 4096
#define NQKV   (3 * DM)          // 3072

typedef short          bf16x8v __attribute__((ext_vector_type(8)));
typedef float          f32x4   __attribute__((ext_vector_type(4)));
typedef float          f32x16  __attribute__((ext_vector_type(16)));
typedef unsigned short u16x4   __attribute__((ext_vector_type(4)));
typedef unsigned short u16x8   __attribute__((ext_vector_type(8)));
typedef unsigned int   u32x2   __attribute__((ext_vector_type(2)));
typedef unsigned int   u32x4   __attribute__((ext_vector_type(4)));

typedef const void __attribute__((address_space(1))) gas_void;
typedef void       __attribute__((address_space(3))) las_void;

static __device__ __forceinline__ unsigned short f2bf(float f) {
    union { float f; uint32_t u; } v; v.f = f;
    uint32_t u = v.u;
    uint32_t r = (u + 0x7fffu + ((u >> 16) & 1u)) >> 16;  // RNE
    return (unsigned short)r;
}

// pack 2 f32 -> 2 bf16 in one u32 (lo = first arg)
static __device__ __forceinline__ uint32_t cvtpk_bf16(float lo, float hi) {
    uint32_t r;
    asm("v_cvt_pk_bf16_f32 %0, %1, %2" : "=v"(r) : "v"(lo), "v"(hi));
    return r;
}
// swap: new_a = {a[0:31], b[0:31]}, new_b = {a[32:63], b[32:63]}
static __device__ __forceinline__ u32x2 pl32swap(uint32_t a, uint32_t b) {
    return __builtin_amdgcn_permlane32_swap(a, b, false, false);
}
static __device__ __forceinline__ float    fbits(uint32_t u) { return __builtin_bit_cast(float, u); }
static __device__ __forceinline__ uint32_t ubits(float f)    { return __builtin_bit_cast(uint32_t, f); }

// ---------------- fp32 -> bf16 elementwise (x) ----------------
__global__ __launch_bounds__(256) void cvt_bf16_kernel(
    const float* __restrict__ in, unsigned short* __restrict__ out, int n8)
{
    const int i = blockIdx.x * 256 + threadIdx.x;
    if (i >= n8) return;
    f32x4 a = *(const f32x4*)(in + (size_t)i * 8);
    f32x4 b = *(const f32x4*)(in + (size_t)i * 8 + 4);
    u16x8 o;
    #pragma unroll
    for (int j = 0; j < 4; ++j) { o[j] = f2bf(a[j]); o[4 + j] = f2bf(b[j]); }
    *(u16x8*)(out + (size_t)i * 8) = o;
}

// ---------------- W [K][N] fp32 -> Wt [N][K] bf16 (tiled transpose) ----------------
__global__ __launch_bounds__(256) void transpose_w_kernel(
    const float* __restrict__ W, unsigned short* __restrict__ Wt, int K, int N)
{
    __shared__ float t[32][33];
    const int tx = threadIdx.x, ty = threadIdx.y;
    const int n0 = blockIdx.x * 32, k0 = blockIdx.y * 32;
    #pragma unroll
    for (int i = 0; i < 4; ++i)
        t[ty * 4 + i][tx] = W[(size_t)(k0 + ty * 4 + i) * N + n0 + tx];
    __syncthreads();
    #pragma unroll
    for (int i = 0; i < 4; ++i)
        Wt[(size_t)(n0 + ty * 4 + i) * K + k0 + tx] = f2bf(t[tx][ty * 4 + i]);
}

// ---------------- GEMM: C[M][N] = A[M][K] * Bt[N][K]^T + bias ----------------
template <int EPI>
__global__ __launch_bounds__(256) void gemm_bt_kernel(
    const unsigned short* __restrict__ A, const unsigned short* __restrict__ Bt,
    const float* __restrict__ bias, void* __restrict__ Cout,
    int M, int N, int K)
{
    __shared__ __attribute__((aligned(16))) unsigned short As[128 * 32];
    __shared__ __attribute__((aligned(16))) unsigned short Bs[128 * 32];

    const int tid  = threadIdx.x;
    const int lane = tid & 63;
    const int w    = tid >> 6;
    const int wr   = w >> 1, wc = w & 1;
    const int lr   = lane & 15, lg = lane >> 4;
    const int m0   = blockIdx.y * 128, n0 = blockIdx.x * 128;

    f32x4 acc[4][4];
    #pragma unroll
    for (int i = 0; i < 4; ++i)
        #pragma unroll
        for (int j = 0; j < 4; ++j) acc[i][j] = (f32x4){0.f, 0.f, 0.f, 0.f};

    for (int kt = 0; kt < K; kt += 32) {
        if (kt) __syncthreads();
        #pragma unroll
        for (int j = 0; j < 2; ++j) {
            const int c  = j * 256 + tid;
            const int r  = c >> 2;
            const int kc = (c & 3) * 8;
            const int cb = j * 256 + (tid & ~63);
            __builtin_amdgcn_global_load_lds(
                (gas_void*)(A + (size_t)(m0 + r) * K + kt + kc),
                (las_void*)((char*)As + (size_t)cb * 16), 16, 0, 0);
            __builtin_amdgcn_global_load_lds(
                (gas_void*)(Bt + (size_t)(n0 + r) * K + kt + kc),
                (las_void*)((char*)Bs + (size_t)cb * 16), 16, 0, 0);
        }
        __syncthreads();

        bf16x8v af[4], bfv[4];
        #pragma unroll
        for (int mi = 0; mi < 4; ++mi)
            af[mi] = *(const bf16x8v*)(&As[(wr * 64 + mi * 16 + lr) * 32 + lg * 8]);
        #pragma unroll
        for (int ni = 0; ni < 4; ++ni)
            bfv[ni] = *(const bf16x8v*)(&Bs[(wc * 64 + ni * 16 + lr) * 32 + lg * 8]);
        #pragma unroll
        for (int mi = 0; mi < 4; ++mi)
            #pragma unroll
            for (int ni = 0; ni < 4; ++ni)
                acc[mi][ni] = __builtin_amdgcn_mfma_f32_16x16x32_bf16(
                    af[mi], bfv[ni], acc[mi][ni], 0, 0, 0);
    }

    const int grow0 = m0 + wr * 64 + lg * 4;
    const int gcol0 = n0 + wc * 64 + lr;
    #pragma unroll
    for (int mi = 0; mi < 4; ++mi)
        #pragma unroll
        for (int ni = 0; ni < 4; ++ni) {
            const int gcol = gcol0 + ni * 16;
            const float bv = bias[gcol];
            #pragma unroll
            for (int r = 0; r < 4; ++r) {
                const size_t idx = (size_t)(grow0 + mi * 16 + r) * N + gcol;
                const float v = acc[mi][ni][r] + bv;
                if (EPI == 0) ((unsigned short*)Cout)[idx] = f2bf(v);
                else          ((float*)Cout)[idx] = v;
            }
        }
}

// ---------------- split QKV -> Q,K [bh][s][64], Vt [bh][64][s] ----------------
__global__ __launch_bounds__(256) void split_qkv_kernel(
    const unsigned short* __restrict__ qkv,
    unsigned short* __restrict__ q, unsigned short* __restrict__ k,
    unsigned short* __restrict__ vt)
{
    const int tid = threadIdx.x;
    const int bh  = blockIdx.y;
    const int h   = bh & 15;
    const int b   = bh >> 4;
    const int s0  = blockIdx.x * 64;
    __shared__ __attribute__((aligned(16))) unsigned short tile[64][68];

    #pragma unroll
    for (int j = 0; j < 4; ++j) {
        const int c  = tid + j * 256;
        const int r  = c >> 4;
        const int c4 = (c & 15) * 4;
        const size_t srow = ((size_t)b * S_LEN + s0 + r) * NQKV + h * 64 + c4;
        u16x4 vq = *(const u16x4*)(qkv + srow);
        u16x4 vk = *(const u16x4*)(qkv + srow + DM);
        u16x4 vv = *(const u16x4*)(qkv + srow + 2 * DM);
        const size_t drow = ((size_t)bh * S_LEN + s0 + r) * DKH + c4;
        *(u16x4*)(q + drow) = vq;
        *(u16x4*)(k + drow) = vk;
        *(u16x4*)&tile[r][c4] = vv;
    }
    __syncthreads();
    #pragma unroll
    for (int j = 0; j < 4; ++j) {
        const int c   = tid + j * 256;
        const int dkr = c >> 4;
        const int s4  = (c & 15) * 4;
        u16x4 o;
        #pragma unroll
        for (int i = 0; i < 4; ++i) o[i] = tile[s4 + i][dkr];
        *(u16x4*)(vt + ((size_t)bh * DKH + dkr) * S_LEN + s0 + s4) = o;
    }
}

// ---------------- flash attention, swapped-operand 32x32, zero LDS ----------------
// 1 wave per block (64 threads). Wave owns 32 q-rows of one (b,h).
// QK^T computed as mfma(A=K, B=Q): lane holds S^T, q = lane&31, kv = crow(r,hi).
// PV computed as mfma(A=V^T, B=P): acc = out^T, col q = lane&31 -> m/l lane-local.
#define EXP_C1 0.18033688f   /* 0.125 * log2(e) : softmax temp in exp2 domain */

#define TILE_STEP(kc, vc, kn, vn, kvn)                                               \
do {                                                                                 \
    f32x16 sc = {};                                                                  \
    __builtin_amdgcn_s_setprio(1);                                                   \
    _Pragma("unroll")                                                                \
    for (int s_ = 0; s_ < 4; ++s_)                                                   \
        sc = __builtin_amdgcn_mfma_f32_32x32x16_bf16(kc[s_], qf[s_], sc, 0, 0, 0);   \
    __builtin_amdgcn_s_setprio(0);                                                   \
    /* prefetch next tile (K rows, V^T rows) while softmax runs */                   \
    const unsigned short* kp_ = Kp + (size_t)(kvn) * DKH;                            \
    _Pragma("unroll")                                                                \
    for (int s_ = 0; s_ < 4; ++s_) kn[s_] = *(const bf16x8v*)(kp_ + s_ * 16);        \
    vn[0] = *(const bf16x8v*)(Vp0 + (kvn));                                          \
    vn[1] = *(const bf16x8v*)(Vp0 + (kvn) + 16);                                     \
    vn[2] = *(const bf16x8v*)(Vp1 + (kvn));                                          \
    vn[3] = *(const bf16x8v*)(Vp1 + (kvn) + 16);                                     \
    /* in-lane max over 16 kv, then combine with partner lane (lane^32) */           \
    float t0_ = fmaxf(sc[0], sc[1]),   t1_ = fmaxf(sc[2], sc[3]);                    \
    float t2_ = fmaxf(sc[4], sc[5]),   t3_ = fmaxf(sc[6], sc[7]);                    \
    float t4_ = fmaxf(sc[8], sc[9]),   t5_ = fmaxf(sc[10], sc[11]);                  \
    float t6_ = fmaxf(sc[12], sc[13]), t7_ = fmaxf(sc[14], sc[15]);                  \
    t0_ = fmaxf(t0_, t1_); t2_ = fmaxf(t2_, t3_);                                    \
    t4_ = fmaxf(t4_, t5_); t6_ = fmaxf(t6_, t7_);                                    \
    float tmax_ = fmaxf(fmaxf(t0_, t2_), fmaxf(t4_, t6_));                           \
    { u32x2 sw_ = pl32swap(ubits(tmax_), ubits(tmax_));                              \
      tmax_ = fmaxf(fbits(sw_[0]), fbits(sw_[1])); }                                 \
    /* T13 defer-max: only rescale when growth > 8 nats (64 raw) */                  \
    if (__any(tmax_ > mraw + 64.f)) {                                                \
        float mn_  = fmaxf(mraw, tmax_);                                             \
        float mcn_ = mn_ * EXP_C1;                                                   \
        float cr_  = exp2f(mc - mcn_);                                               \
        mraw = mn_; mc = mcn_;                                                       \
        lsum *= cr_;                                                                 \
        _Pragma("unroll")                                                            \
        for (int r_ = 0; r_ < 16; ++r_) { acc0[r_] *= cr_; acc1[r_] *= cr_; }        \
    }                                                                                \
    float pe_[16];                                                                   \
    _Pragma("unroll")                                                                \
    for (int r_ = 0; r_ < 16; ++r_)                                                  \
        pe_[r_] = exp2f(fmaf(sc[r_], EXP_C1, -mc));                                  \
    float u0_ = (pe_[0] + pe_[1]) + (pe_[2] + pe_[3]);                               \
    float u1_ = (pe_[4] + pe_[5]) + (pe_[6] + pe_[7]);                               \
    float u2_ = (pe_[8] + pe_[9]) + (pe_[10] + pe_[11]);                             \
    float u3_ = (pe_[12] + pe_[13]) + (pe_[14] + pe_[15]);                           \
    float ss_ = (u0_ + u1_) + (u2_ + u3_);                                           \
    { u32x2 sw_ = pl32swap(ubits(ss_), ubits(ss_));                                  \
      ss_ = fbits(sw_[0]) + fbits(sw_[1]); }                                         \
    lsum += ss_;                                                                     \
    /* P -> bf16 B-fragments: cvt_pk pairs + permlane32_swap (T12 recipe) */         \
    uint32_t a01_ = cvtpk_bf16(pe_[0],  pe_[1]),  a23_ = cvtpk_bf16(pe_[2],  pe_[3]);  \
    uint32_t a45_ = cvtpk_bf16(pe_[4],  pe_[5]),  a67_ = cvtpk_bf16(pe_[6],  pe_[7]);  \
    uint32_t b01_ = cvtpk_bf16(pe_[8],  pe_[9]),  b23_ = cvtpk_bf16(pe_[10], pe_[11]); \
    uint32_t b45_ = cvtpk_bf16(pe_[12], pe_[13]), b67_ = cvtpk_bf16(pe_[14], pe_[15]); \
    u32x2 s0_ = pl32swap(a01_, a45_);                                                \
    u32x2 s1_ = pl32swap(a23_, a67_);                                                \
    u32x2 s2_ = pl32swap(b01_, b45_);                                                \
    u32x2 s3_ = pl32swap(b23_, b67_);                                                \
    u32x4 w0_ = { s0_[0], s1_[0], s0_[1], s1_[1] };                                  \
    u32x4 w1_ = { s2_[0], s3_[0], s2_[1], s3_[1] };                                  \
    bf16x8v pa0_ = __builtin_bit_cast(bf16x8v, w0_);                                 \
    bf16x8v pa1_ = __builtin_bit_cast(bf16x8v, w1_);                                 \
    __builtin_amdgcn_s_setprio(1);                                                   \
    acc0 = __builtin_amdgcn_mfma_f32_32x32x16_bf16(vc[0], pa0_, acc0, 0, 0, 0);      \
    acc0 = __builtin_amdgcn_mfma_f32_32x32x16_bf16(vc[1], pa1_, acc0, 0, 0, 0);      \
    acc1 = __builtin_amdgcn_mfma_f32_32x32x16_bf16(vc[2], pa0_, acc1, 0, 0, 0);      \
    acc1 = __builtin_amdgcn_mfma_f32_32x32x16_bf16(vc[3], pa1_, acc1, 0, 0, 0);      \
    __builtin_amdgcn_s_setprio(0);                                                   \
} while (0)

__global__ __launch_bounds__(64) void attn_kernel(
    const unsigned short* __restrict__ Q, const unsigned short* __restrict__ K,
    const unsigned short* __restrict__ Vt, unsigned short* __restrict__ O)
{
    const int lane = threadIdx.x;
    const int lo = lane & 31;
    const int hi = lane >> 5;

    // T1: XCD-chunked bijective swizzle; 2048 blocks = 8 XCDs x 256.
    const int flat = blockIdx.x;
    const int virt = (flat & 7) * 256 + (flat >> 3);
    const int bh = virt >> 6;          // 0..31
    const int qt = virt & 63;          // 0..63
    const int b = bh >> 4, h = bh & 15;
    const int q0 = qt * 32;

    // Q fragments (B-operand): lane holds Q[q0+lo][s*16 + hi*8 .. +7]
    const unsigned short* Qp = Q + ((size_t)bh * S_LEN + q0 + lo) * DKH + hi * 8;
    bf16x8v qf[4];
    #pragma unroll
    for (int s = 0; s < 4; ++s) qf[s] = *(const bf16x8v*)(Qp + s * 16);

    // K fragment base (A-operand): lane holds K[kv0+lo][s*16 + hi*8 .. +7]
    const unsigned short* Kp  = K + (size_t)bh * S_LEN * DKH + (size_t)lo * DKH + hi * 8;
    // V^T fragment bases (A-operand): lane holds Vt[n*32+lo][kv0 + ks*16 + hi*8 .. +7]
    const unsigned short* Vp0 = Vt + ((size_t)bh * DKH + lo) * S_LEN + hi * 8;
    const unsigned short* Vp1 = Vp0 + (size_t)32 * S_LEN;

    f32x16 acc0 = {}, acc1 = {};       // out^T: rows d = n*32 + crow(r,hi), col q = lo
    float mraw = -__builtin_inff(), lsum = 0.f, mc = 0.f;

    bf16x8v ka[4], kb2[4], va[4], vb2[4];
    #pragma unroll
    for (int s = 0; s < 4; ++s) ka[s] = *(const bf16x8v*)(Kp + s * 16);
    va[0] = *(const bf16x8v*)(Vp0);
    va[1] = *(const bf16x8v*)(Vp0 + 16);
    va[2] = *(const bf16x8v*)(Vp1);
    va[3] = *(const bf16x8v*)(Vp1 + 16);

    for (int kv0 = 0; kv0 < S_LEN; kv0 += 64) {
        TILE_STEP(ka, va, kb2, vb2, kv0 + 32);
        const int nx = (kv0 + 64 < S_LEN) ? (kv0 + 64) : 0;
        TILE_STEP(kb2, vb2, ka, va, nx);
    }

    const float linv = 1.f / lsum;
    // lane writes row q = q0+lo, cols h*64 + {n*32 + 8g + 4hi + 0..3}
    unsigned short* Orow = O + ((size_t)b * S_LEN + q0 + lo) * DM + h * 64 + hi * 4;
    #pragma unroll
    for (int g = 0; g < 4; ++g) {
        u16x4 st0, st1;
        #pragma unroll
        for (int k2 = 0; k2 < 4; ++k2) {
            st0[k2] = f2bf(acc0[g * 4 + k2] * linv);
            st1[k2] = f2bf(acc1[g * 4 + k2] * linv);
        }
        *(u16x4*)(Orow + g * 8)      = st0;
        *(u16x4*)(Orow + 32 + g * 8) = st1;
    }
}

// ---------------- host launcher ----------------
extern "C" void kernel_launch(void* const* d_in, const int* in_sizes, int n_in,
                              void* d_out, int out_size, void* d_ws, size_t ws_size,
                              hipStream_t stream)
{
    const float* x    = (const float*)d_in[0];
    const float* Wqkv = (const float*)d_in[1];
    const float* bqkv = (const float*)d_in[2];
    const float* Wout = (const float*)d_in[3];
    const float* bout = (const float*)d_in[4];
    float* out = (float*)d_out;

    char* ws = (char*)d_ws;
    unsigned short* xb     = (unsigned short*)(ws);
    unsigned short* wqkv_t = (unsigned short*)(ws + 8388608);
    unsigned short* wout_t = (unsigned short*)(ws + 14680064);
    unsigned short* qkvb   = (unsigned short*)(ws + 16777216);
    unsigned short* kb     = (unsigned short*)(ws + 41943040);
    unsigned short* vtb    = (unsigned short*)(ws + 50331648);
    unsigned short* qb     = xb;    // alias: x bf16 dead after QKV GEMM
    unsigned short* attn_o = qkvb;  // alias: qkv dead after split

    cvt_bf16_kernel<<<2048, 256, 0, stream>>>(x, xb, (M_ROWS * DM) / 8);
    transpose_w_kernel<<<dim3(NQKV / 32, DM / 32), dim3(32, 8), 0, stream>>>(Wqkv, wqkv_t, DM, NQKV);
    transpose_w_kernel<<<dim3(DM / 32, DM / 32), dim3(32, 8), 0, stream>>>(Wout, wout_t, DM, DM);
    gemm_bt_kernel<0><<<dim3(NQKV / 128, M_ROWS / 128), 256, 0, stream>>>(
        xb, wqkv_t, bqkv, (void*)qkvb, M_ROWS, NQKV, DM);
    split_qkv_kernel<<<dim3(S_LEN / 64, BATCH * NH), 256, 0, stream>>>(qkvb, qb, kb, vtb);
    attn_kernel<<<2048, 64, 0, stream>>>(qb, kb, vtb, attn_o);
    gemm_bt_kernel<1><<<dim3(DM / 128, M_ROWS / 128), 256, 0, stream>>>(
        attn_o, wout_t, bout, (void*)out, M_ROWS, DM, DM);
}